// Round 1
// baseline (3420.314 us; speedup 1.0000x reference)
//
#include <hip/hip_runtime.h>
#include <hip/hip_bf16.h>

// Problem constants (HierAttn): B=8, T=4096, E=1024, H=16, DH=64
// W0=128, CS=8, W1=16, W2=8 -> bank = 128 + 16 + 8 = 152 keys, from last 256 tokens.
#define B_    8
#define T_    4096
#define E_    1024
#define H_    16
#define DH_   64
#define NK0   128
#define NKB   152
#define LAST  256

// ---------------------------------------------------------------------------
// W_eff = W + 2.0 * A @ Bm   (rank-8 LoRA fold)
// ---------------------------------------------------------------------------
__global__ __launch_bounds__(256) void weff_kernel(
    const float* __restrict__ W, const float* __restrict__ A,
    const float* __restrict__ Bm, float* __restrict__ out)
{
  int g = blockIdx.x * 256 + threadIdx.x;      // E*E/4 = 262144 threads
  int o = g >> 8;
  int i = (g & 255) * 4;
  float4 acc = *(const float4*)(W + (long)o * E_ + i);
  float a[8];
  *(float4*)&a[0] = *(const float4*)(A + o * 8);
  *(float4*)&a[4] = *(const float4*)(A + o * 8 + 4);
#pragma unroll
  for (int r = 0; r < 8; ++r) {
    float4 bv = *(const float4*)(Bm + (long)r * E_ + i);
    float s = 2.0f * a[r];
    acc.x += s * bv.x; acc.y += s * bv.y; acc.z += s * bv.z; acc.w += s * bv.w;
  }
  *(float4*)(out + (long)o * E_ + i) = acc;
}

// ---------------------------------------------------------------------------
// C[M][E] = A[M][E] @ W[E][E]^T  (fp32, BM=BN=128, BK=16, 256 thr, 8x8/thread)
// GATHER: A rows come from the last 256 tokens of each batch of x (B,T,E).
// blockIdx.z selects (W0p,C0p) vs (W1p,C1p) so K and V run in one launch.
// ---------------------------------------------------------------------------
template <bool GATHER>
__global__ __launch_bounds__(256) void gemm_xwt(
    const float* __restrict__ A,
    const float* __restrict__ W0p, float* __restrict__ C0p,
    const float* __restrict__ W1p, float* __restrict__ C1p)
{
  constexpr int BM = 128, BN = 128, BK = 16;
  const float* W = (blockIdx.z == 0) ? W0p : W1p;
  float*       C = (blockIdx.z == 0) ? C0p : C1p;

  __shared__ float As[BK][BM];   // transposed tiles: [k][row]
  __shared__ float Ws[BK][BN];

  const int tid = threadIdx.x;
  const int m0 = blockIdx.y * BM;
  const int n0 = blockIdx.x * BN;
  long arow0 = GATHER ? ((long)(m0 >> 8) * T_ + (T_ - LAST) + (m0 & 255))
                      : (long)m0;

  const int r  = tid >> 2;      // 0..63  (row within half-tile)
  const int cq = tid & 3;       // 0..3   (float4 column)
  const float* Ap = A + (arow0 + r) * (long)E_ + cq * 4;
  const float* Wp = W + ((long)(n0 + r)) * E_ + cq * 4;
  const int tx = tid & 15, ty = tid >> 4;

  float4 pa0 = *(const float4*)(Ap);
  float4 pa1 = *(const float4*)(Ap + (long)64 * E_);
  float4 pw0 = *(const float4*)(Wp);
  float4 pw1 = *(const float4*)(Wp + (long)64 * E_);

  float acc[8][8] = {};

  for (int t = 0; t < E_ / BK; ++t) {
    __syncthreads();              // previous inner-loop reads done
#pragma unroll
    for (int i = 0; i < 4; ++i) {
      As[cq * 4 + i][r]      = ((const float*)&pa0)[i];
      As[cq * 4 + i][r + 64] = ((const float*)&pa1)[i];
      Ws[cq * 4 + i][r]      = ((const float*)&pw0)[i];
      Ws[cq * 4 + i][r + 64] = ((const float*)&pw1)[i];
    }
    __syncthreads();
    if (t < E_ / BK - 1) {        // prefetch next K-tile into registers
      int ko = (t + 1) * BK;
      pa0 = *(const float4*)(Ap + ko);
      pa1 = *(const float4*)(Ap + ko + (long)64 * E_);
      pw0 = *(const float4*)(Wp + ko);
      pw1 = *(const float4*)(Wp + ko + (long)64 * E_);
    }
#pragma unroll
    for (int kk = 0; kk < BK; ++kk) {
      float4 a0 = *(const float4*)&As[kk][ty * 4];
      float4 a1 = *(const float4*)&As[kk][64 + ty * 4];
      float4 b0 = *(const float4*)&Ws[kk][tx * 4];
      float4 b1 = *(const float4*)&Ws[kk][64 + tx * 4];
      const float aa[8] = {a0.x, a0.y, a0.z, a0.w, a1.x, a1.y, a1.z, a1.w};
      const float bb[8] = {b0.x, b0.y, b0.z, b0.w, b1.x, b1.y, b1.z, b1.w};
#pragma unroll
      for (int i = 0; i < 8; ++i)
#pragma unroll
        for (int j = 0; j < 8; ++j)
          acc[i][j] += aa[i] * bb[j];
    }
  }

#pragma unroll
  for (int i = 0; i < 8; ++i) {
    long m = m0 + (i < 4 ? ty * 4 + i : 64 + ty * 4 + (i - 4));
    float4 o0 = make_float4(acc[i][0], acc[i][1], acc[i][2], acc[i][3]);
    float4 o1 = make_float4(acc[i][4], acc[i][5], acc[i][6], acc[i][7]);
    *(float4*)(C + m * E_ + n0 + tx * 4)      = o0;
    *(float4*)(C + m * E_ + n0 + 64 + tx * 4) = o1;
  }
}

// ---------------------------------------------------------------------------
// Build the 152-entry K/V bank from the last-256-token K/V projections.
// j in [0,128): K0 (identity, rows 128+j); [128,144): mean-8; [144,152): mean-16
// ---------------------------------------------------------------------------
__global__ __launch_bounds__(256) void bank_kernel(
    const float* __restrict__ Kl, const float* __restrict__ Vl,
    float* __restrict__ Kb, float* __restrict__ Vb)
{
  int g = blockIdx.x * 256 + threadIdx.x;       // B*NKB*256 threads
  if (g >= B_ * NKB * 256) return;
  int c = (g & 255) * 4;
  int j = (g >> 8) % NKB;
  int b = g / (NKB * 256);
  const long base = (long)b * LAST * E_;
  float4 ks, vs;
  if (j < NK0) {
    long rr = base + (long)(128 + j) * E_ + c;
    ks = *(const float4*)(Kl + rr);
    vs = *(const float4*)(Vl + rr);
  } else {
    int n  = (j < 144) ? 8 : 16;
    int r0 = (j < 144) ? (j - 128) * 8 : (j - 144) * 16;
    float4 ak = make_float4(0, 0, 0, 0), av = make_float4(0, 0, 0, 0);
    for (int u = 0; u < n; ++u) {
      long rr = base + (long)(r0 + u) * E_ + c;
      float4 kv = *(const float4*)(Kl + rr);
      float4 vv = *(const float4*)(Vl + rr);
      ak.x += kv.x; ak.y += kv.y; ak.z += kv.z; ak.w += kv.w;
      av.x += vv.x; av.y += vv.y; av.z += vv.z; av.w += vv.w;
    }
    float inv = 1.0f / (float)n;
    ks = make_float4(ak.x * inv, ak.y * inv, ak.z * inv, ak.w * inv);
    vs = make_float4(av.x * inv, av.y * inv, av.z * inv, av.w * inv);
  }
  long o = ((long)b * NKB + j) * E_ + c;
  *(float4*)(Kb + o) = ks;
  *(float4*)(Vb + o) = vs;
}

// ---------------------------------------------------------------------------
// Fused 3-level attention. Block = (64 queries) x (b,h). 256 threads:
// each query owned by a 4-lane quad (d-split 16 each). Scores for all 152
// keys cached in registers (fully unrolled -> static indices), per-group
// softmax, combined with softmax(lvl_w), single PV pass.
// K staged in LDS for pass 1, then the same LDS is re-staged with V.
// ---------------------------------------------------------------------------
__global__ __launch_bounds__(256) void attn_kernel(
    const float* __restrict__ Q, const float* __restrict__ Kb,
    const float* __restrict__ Vb, const float* __restrict__ lvl,
    float* __restrict__ AO)
{
  __shared__ float KV[NKB][DH_];      // 38 KiB
  const int tid = threadIdx.x;
  const int b = blockIdx.z, h = blockIdx.y;
  const int t0 = blockIdx.x * 64;

  const float* Ksrc = Kb + ((long)b * NKB) * E_ + h * DH_;
  const float* Vsrc = Vb + ((long)b * NKB) * E_ + h * DH_;

  // stage K
  for (int g = tid; g < NKB * 16; g += 256) {
    int j = g >> 4, dq = (g & 15) * 4;
    *(float4*)&KV[j][dq] = *(const float4*)(Ksrc + (long)j * E_ + dq);
  }

  // level weights = softmax(lvl_w)
  float l0 = lvl[0], l1 = lvl[1], l2 = lvl[2];
  float lm = fmaxf(l0, fmaxf(l1, l2));
  float e0 = __expf(l0 - lm), e1 = __expf(l1 - lm), e2 = __expf(l2 - lm);
  float einv = 1.0f / (e0 + e1 + e2);

  const int ql = tid >> 2;     // query within tile (0..63)
  const int rq = tid & 3;      // d-quad (0..3), covers d = rq*16 .. rq*16+15
  const float* Qrow = Q + ((long)b * T_ + t0 + ql) * E_ + h * DH_ + rq * 16;
  float q[16];
  *(float4*)&q[0]  = *(const float4*)(Qrow);
  *(float4*)&q[4]  = *(const float4*)(Qrow + 4);
  *(float4*)&q[8]  = *(const float4*)(Qrow + 8);
  *(float4*)&q[12] = *(const float4*)(Qrow + 12);

  __syncthreads();

  // pass 1: scores. Lane keeps s for keys j == rq (mod 4): s[j>>2]
  float s[NKB / 4];
#pragma unroll
  for (int j = 0; j < NKB; ++j) {
    float d = 0.f;
#pragma unroll
    for (int i = 0; i < 16; i += 4) {
      float4 kv = *(const float4*)&KV[j][rq * 16 + i];
      d += q[i] * kv.x + q[i + 1] * kv.y + q[i + 2] * kv.z + q[i + 3] * kv.w;
    }
    d += __shfl_xor(d, 1);
    d += __shfl_xor(d, 2);
    if ((j & 3) == rq) s[j >> 2] = d * 0.125f;   // 1/sqrt(64)
  }

  __syncthreads();                // all pass-1 K reads complete
  // re-stage LDS with V (softmax below overlaps the latency)
  for (int g = tid; g < NKB * 16; g += 256) {
    int j = g >> 4, dq = (g & 15) * 4;
    *(float4*)&KV[j][dq] = *(const float4*)(Vsrc + (long)j * E_ + dq);
  }

  // group softmaxes over idx ranges: [0,32)=level0, [32,36)=level1, [36,38)=level2
  {
    float mx = -1e30f;
#pragma unroll
    for (int i = 0; i < 32; ++i) mx = fmaxf(mx, s[i]);
    mx = fmaxf(mx, __shfl_xor(mx, 1)); mx = fmaxf(mx, __shfl_xor(mx, 2));
    float sm = 0.f;
#pragma unroll
    for (int i = 0; i < 32; ++i) { s[i] = __expf(s[i] - mx); sm += s[i]; }
    sm += __shfl_xor(sm, 1); sm += __shfl_xor(sm, 2);
    float f = (e0 * einv) / sm;
#pragma unroll
    for (int i = 0; i < 32; ++i) s[i] *= f;
  }
  {
    float mx = -1e30f;
#pragma unroll
    for (int i = 32; i < 36; ++i) mx = fmaxf(mx, s[i]);
    mx = fmaxf(mx, __shfl_xor(mx, 1)); mx = fmaxf(mx, __shfl_xor(mx, 2));
    float sm = 0.f;
#pragma unroll
    for (int i = 32; i < 36; ++i) { s[i] = __expf(s[i] - mx); sm += s[i]; }
    sm += __shfl_xor(sm, 1); sm += __shfl_xor(sm, 2);
    float f = (e1 * einv) / sm;
#pragma unroll
    for (int i = 32; i < 36; ++i) s[i] *= f;
  }
  {
    float mx = -1e30f;
#pragma unroll
    for (int i = 36; i < 38; ++i) mx = fmaxf(mx, s[i]);
    mx = fmaxf(mx, __shfl_xor(mx, 1)); mx = fmaxf(mx, __shfl_xor(mx, 2));
    float sm = 0.f;
#pragma unroll
    for (int i = 36; i < 38; ++i) { s[i] = __expf(s[i] - mx); sm += s[i]; }
    sm += __shfl_xor(sm, 1); sm += __shfl_xor(sm, 2);
    float f = (e2 * einv) / sm;
#pragma unroll
    for (int i = 36; i < 38; ++i) s[i] *= f;
  }

  __syncthreads();                // V staged

  // pass 2: PV
  float acc[16] = {};
#pragma unroll
  for (int j = 0; j < NKB; ++j) {
    float pj = __shfl(s[j >> 2], j & 3, 4);
#pragma unroll
    for (int i = 0; i < 16; i += 4) {
      float4 vv = *(const float4*)&KV[j][rq * 16 + i];
      acc[i]     += pj * vv.x; acc[i + 1] += pj * vv.y;
      acc[i + 2] += pj * vv.z; acc[i + 3] += pj * vv.w;
    }
  }

  float* Op = AO + ((long)b * T_ + t0 + ql) * E_ + h * DH_ + rq * 16;
  *(float4*)(Op)      = *(float4*)&acc[0];
  *(float4*)(Op + 4)  = *(float4*)&acc[4];
  *(float4*)(Op + 8)  = *(float4*)&acc[8];
  *(float4*)(Op + 12) = *(float4*)&acc[12];
}

// ---------------------------------------------------------------------------
extern "C" void kernel_launch(void* const* d_in, const int* in_sizes, int n_in,
                              void* d_out, int out_size, void* d_ws, size_t ws_size,
                              hipStream_t stream)
{
  const float* x    = (const float*)d_in[0];
  const float* Wq_w = (const float*)d_in[1];
  const float* Wq_A = (const float*)d_in[2];
  const float* Wq_B = (const float*)d_in[3];
  const float* Wk_w = (const float*)d_in[4];
  const float* Wk_A = (const float*)d_in[5];
  const float* Wk_B = (const float*)d_in[6];
  const float* Wv_w = (const float*)d_in[7];
  const float* Wv_A = (const float*)d_in[8];
  const float* Wv_B = (const float*)d_in[9];
  const float* Wp   = (const float*)d_in[10];
  const float* lvl  = (const float*)d_in[11];
  float* out = (float*)d_out;

  // workspace layout (floats); total ~307.8 MB
  float* ws  = (float*)d_ws;
  float* Weq = ws;                                   // 1M
  float* Wek = Weq + (1 << 20);                      // 1M
  float* Wev = Wek + (1 << 20);                      // 1M
  float* Qb  = Wev + (1 << 20);                      // 33.55M (B,T,E)
  float* Kl  = Qb + (long)B_ * T_ * E_;              // 2M (B,256,E)
  float* Vl  = Kl + (long)B_ * LAST * E_;            // 2M
  float* Kb  = Vl + (long)B_ * LAST * E_;            // 1.245M (B,152,E)
  float* Vb  = Kb + (long)B_ * NKB * E_;             // 1.245M
  float* AO  = Vb + (long)B_ * NKB * E_;             // 33.55M

  // 1) fold LoRA into effective weights
  weff_kernel<<<1024, 256, 0, stream>>>(Wq_w, Wq_A, Wq_B, Weq);
  weff_kernel<<<1024, 256, 0, stream>>>(Wk_w, Wk_A, Wk_B, Wek);
  weff_kernel<<<1024, 256, 0, stream>>>(Wv_w, Wv_A, Wv_B, Wev);

  // 2) Q projection over all tokens: (32768 x 1024) @ (1024 x 1024)^T
  gemm_xwt<false><<<dim3(8, 256, 1), 256, 0, stream>>>(x, Weq, Qb, Weq, Qb);

  // 3) K,V projections over last 256 tokens per batch (gathered), one launch
  gemm_xwt<true><<<dim3(8, 16, 2), 256, 0, stream>>>(x, Wek, Kl, Wev, Vl);

  // 4) hierarchical K/V bank (152 keys per batch)
  bank_kernel<<<(B_ * NKB * 256) / 256, 256, 0, stream>>>(Kl, Vl, Kb, Vb);

  // 5) fused 3-level attention -> AO (B,T,E)
  attn_kernel<<<dim3(T_ / 64, H_, B_), 256, 0, stream>>>(Qb, Kb, Vb, lvl, AO);

  // 6) output projection: out = AO @ Wp^T
  gemm_xwt<false><<<dim3(8, 256, 1), 256, 0, stream>>>(AO, Wp, out, Wp, out);

  // 7) recon = 0.0
  hipMemsetAsync(out + (long)B_ * T_ * E_, 0, sizeof(float), stream);
}

// Round 2
// 1417.271 us; speedup vs baseline: 2.4133x; 2.4133x over previous
//
#include <hip/hip_runtime.h>
#include <hip/hip_bf16.h>
#include <cstdint>

// HierAttn: B=8, T=4096, E=1024, H=16, DH=64; bank = 128 + 16 + 8 = 152 keys
#define B_    8
#define T_    4096
#define E_    1024
#define H_    16
#define DH_   64
#define NK0   128
#define NKB   152
#define LAST  256

typedef __attribute__((ext_vector_type(8))) short bf16x8;
typedef __attribute__((ext_vector_type(4))) float f32x4;

#define GLD16(gp, lp)                                                        \
  __builtin_amdgcn_global_load_lds(                                          \
      (const __attribute__((address_space(1))) void*)(const void*)(gp),      \
      (__attribute__((address_space(3))) void*)(unsigned)(uintptr_t)(void*)(lp), \
      16, 0, 0)

__device__ __forceinline__ void bf16split(float v, short& h, short& l) {
  __hip_bfloat16 bh = __float2bfloat16(v);
  float r = v - __bfloat162float(bh);
  __hip_bfloat16 bl = __float2bfloat16(r);
  h = *reinterpret_cast<short*>(&bh);
  l = *reinterpret_cast<short*>(&bl);
}

// ---------------------------------------------------------------------------
// split fp32 -> (bf16 hi, bf16 lo), grid-stride over float4 groups
// ---------------------------------------------------------------------------
__global__ __launch_bounds__(256) void split_kernel(
    const float* __restrict__ src, short* __restrict__ h, short* __restrict__ l,
    int n4)
{
  int stride = gridDim.x * 256;
  for (int i = blockIdx.x * 256 + threadIdx.x; i < n4; i += stride) {
    float4 v = *(const float4*)(src + (long)i * 4);
    short4 hs, ls;
    bf16split(v.x, hs.x, ls.x); bf16split(v.y, hs.y, ls.y);
    bf16split(v.z, hs.z, ls.z); bf16split(v.w, hs.w, ls.w);
    *(short4*)(h + (long)i * 4) = hs;
    *(short4*)(l + (long)i * 4) = ls;
  }
}

// ---------------------------------------------------------------------------
// W_eff = W + 2 * A @ Bm, emitted as bf16 hi/lo pair
// ---------------------------------------------------------------------------
__global__ __launch_bounds__(256) void weff_split_kernel(
    const float* __restrict__ W, const float* __restrict__ A,
    const float* __restrict__ Bm, short* __restrict__ Wh, short* __restrict__ Wl)
{
  int g = blockIdx.x * 256 + threadIdx.x;      // E*E/4 threads
  int o = g >> 8;
  int i = (g & 255) * 4;
  float4 acc = *(const float4*)(W + (long)o * E_ + i);
  float a[8];
  *(float4*)&a[0] = *(const float4*)(A + o * 8);
  *(float4*)&a[4] = *(const float4*)(A + o * 8 + 4);
#pragma unroll
  for (int r = 0; r < 8; ++r) {
    float4 bv = *(const float4*)(Bm + (long)r * E_ + i);
    float s = 2.0f * a[r];
    acc.x += s * bv.x; acc.y += s * bv.y; acc.z += s * bv.z; acc.w += s * bv.w;
  }
  short4 hs, ls;
  bf16split(acc.x, hs.x, ls.x); bf16split(acc.y, hs.y, ls.y);
  bf16split(acc.z, hs.z, ls.z); bf16split(acc.w, hs.w, ls.w);
  *(short4*)(Wh + (long)o * E_ + i) = hs;
  *(short4*)(Wl + (long)o * E_ + i) = ls;
}

// ---------------------------------------------------------------------------
// Split-bf16 MFMA GEMM: C[M][N] (fp32) = A[M][K] @ W[N][K]^T via
// Ah*Wh + Ah*Wl + Al*Wh (fp32 acc). 128x128 tile, BK=32, 256 thr (4 waves 2x2).
// Staging: global_load_lds w=16, linear LDS dest, source pre-swizzled with
// c_phys = c_log ^ ((r>>1)&3); reads apply the same XOR (involution).
// GATHER: A rows gathered from last-256 tokens per batch of an x-like (B,T,E).
// ---------------------------------------------------------------------------
template <bool GATHER>
__global__ __launch_bounds__(256, 2) void gemm_split_bt(
    const short* __restrict__ Ah, const short* __restrict__ Al,
    const short* __restrict__ B0h, const short* __restrict__ B0l, float* __restrict__ C0,
    const short* __restrict__ B1h, const short* __restrict__ B1l, float* __restrict__ C1)
{
  const short* Bh = (blockIdx.z == 0) ? B0h : B1h;
  const short* Bl = (blockIdx.z == 0) ? B0l : B1l;
  float*       C  = (blockIdx.z == 0) ? C0  : C1;

  __shared__ short lds[4 * 128 * 32];          // Ah | Al | Bh | Bl, 32 KiB
  short* tAh = lds;
  short* tAl = lds + 4096;
  short* tBh = lds + 8192;
  short* tBl = lds + 12288;

  const int tid = threadIdx.x;
  const int l = tid & 63, w = tid >> 6;        // lane, wave (2x2 wave grid)
  const int m0 = blockIdx.y * 128, n0 = blockIdx.x * 128;

  // staging geometry: per tile this thread covers q0 = w*128 + l and q0+64
  const int q0 = w * 128 + l, q1 = q0 + 64;
  const int r0 = q0 >> 2, c0 = (q0 & 3) ^ ((r0 >> 1) & 3);
  const int r1 = q1 >> 2, c1 = (q1 & 3) ^ ((r1 >> 1) & 3);

  long ar0, ar1;
  if (GATHER) {
    ar0 = (long)((m0 + r0) >> 8) * T_ + (T_ - LAST) + ((m0 + r0) & 255);
    ar1 = (long)((m0 + r1) >> 8) * T_ + (T_ - LAST) + ((m0 + r1) & 255);
  } else { ar0 = m0 + r0; ar1 = m0 + r1; }

  const short* pAh0 = Ah + ar0 * E_ + c0 * 8;
  const short* pAh1 = Ah + ar1 * E_ + c1 * 8;
  const short* pAl0 = Al + ar0 * E_ + c0 * 8;
  const short* pAl1 = Al + ar1 * E_ + c1 * 8;
  const short* pBh0 = Bh + (long)(n0 + r0) * E_ + c0 * 8;
  const short* pBh1 = Bh + (long)(n0 + r1) * E_ + c1 * 8;
  const short* pBl0 = Bl + (long)(n0 + r0) * E_ + c0 * 8;
  const short* pBl1 = Bl + (long)(n0 + r1) * E_ + c1 * 8;

  // wave-uniform LDS staging destinations (shorts)
  short* dAh0 = tAh + w * 1024; short* dAh1 = dAh0 + 512;
  short* dAl0 = tAl + w * 1024; short* dAl1 = dAl0 + 512;
  short* dBh0 = tBh + w * 1024; short* dBh1 = dBh0 + 512;
  short* dBl0 = tBl + w * 1024; short* dBl1 = dBl0 + 512;

  // fragment read offsets (shorts): row = base + (l&15), chunk = (l>>4) ^ f(row)
  const int fr = l & 15;
  const int fc = ((l >> 4) ^ ((fr >> 1) & 3)) * 8;
  const int aoff = ((w >> 1) * 64 + fr) * 32 + fc;   // + mi*512
  const int boff = ((w & 1)  * 64 + fr) * 32 + fc;   // + ni*512

  f32x4 acc[4][4] = {};

  for (int t = 0; t < E_ / 32; ++t) {
    GLD16(pAh0, dAh0); GLD16(pAh1, dAh1);
    GLD16(pAl0, dAl0); GLD16(pAl1, dAl1);
    GLD16(pBh0, dBh0); GLD16(pBh1, dBh1);
    GLD16(pBl0, dBl0); GLD16(pBl1, dBl1);
    pAh0 += 32; pAh1 += 32; pAl0 += 32; pAl1 += 32;
    pBh0 += 32; pBh1 += 32; pBl0 += 32; pBl1 += 32;
    __syncthreads();                       // drains vmcnt (gload_lds) + orders

    bf16x8 fah[4], fal[4], fbh[4], fbl[4];
#pragma unroll
    for (int mi = 0; mi < 4; ++mi) {
      fah[mi] = *(const bf16x8*)(tAh + aoff + mi * 512);
      fal[mi] = *(const bf16x8*)(tAl + aoff + mi * 512);
    }
#pragma unroll
    for (int ni = 0; ni < 4; ++ni) {
      fbh[ni] = *(const bf16x8*)(tBh + boff + ni * 512);
      fbl[ni] = *(const bf16x8*)(tBl + boff + ni * 512);
    }
#pragma unroll
    for (int mi = 0; mi < 4; ++mi)
#pragma unroll
      for (int ni = 0; ni < 4; ++ni) {
        f32x4 u = __builtin_amdgcn_mfma_f32_16x16x32_bf16(fah[mi], fbh[ni], acc[mi][ni], 0, 0, 0);
        u = __builtin_amdgcn_mfma_f32_16x16x32_bf16(fah[mi], fbl[ni], u, 0, 0, 0);
        acc[mi][ni] = __builtin_amdgcn_mfma_f32_16x16x32_bf16(fal[mi], fbh[ni], u, 0, 0, 0);
      }
    __syncthreads();                       // protect LDS reuse next iter
  }

  // epilogue: D lane map col = l&15, row = (l>>4)*4 + v   [m89-verified]
#pragma unroll
  for (int mi = 0; mi < 4; ++mi)
#pragma unroll
    for (int ni = 0; ni < 4; ++ni) {
      long r = m0 + (w >> 1) * 64 + mi * 16 + (l >> 4) * 4;
      int  c = n0 + (w & 1)  * 64 + ni * 16 + fr;
#pragma unroll
      for (int v = 0; v < 4; ++v)
        C[(r + v) * E_ + c] = acc[mi][ni][v];
    }
}

// ---------------------------------------------------------------------------
// Hierarchical K/V bank (152 keys per batch) from last-256-token K/V (fp32)
// ---------------------------------------------------------------------------
__global__ __launch_bounds__(256) void bank_kernel(
    const float* __restrict__ Kl, const float* __restrict__ Vl,
    float* __restrict__ Kb, float* __restrict__ Vb)
{
  int g = blockIdx.x * 256 + threadIdx.x;
  if (g >= B_ * NKB * 256) return;
  int c = (g & 255) * 4;
  int j = (g >> 8) % NKB;
  int b = g / (NKB * 256);
  const long base = (long)b * LAST * E_;
  float4 ks, vs;
  if (j < NK0) {
    long rr = base + (long)(128 + j) * E_ + c;
    ks = *(const float4*)(Kl + rr);
    vs = *(const float4*)(Vl + rr);
  } else {
    int n  = (j < 144) ? 8 : 16;
    int r0 = (j < 144) ? (j - 128) * 8 : (j - 144) * 16;
    float4 ak = make_float4(0, 0, 0, 0), av = make_float4(0, 0, 0, 0);
    for (int u = 0; u < n; ++u) {
      long rr = base + (long)(r0 + u) * E_ + c;
      float4 kv = *(const float4*)(Kl + rr);
      float4 vv = *(const float4*)(Vl + rr);
      ak.x += kv.x; ak.y += kv.y; ak.z += kv.z; ak.w += kv.w;
      av.x += vv.x; av.y += vv.y; av.z += vv.z; av.w += vv.w;
    }
    float inv = 1.0f / (float)n;
    ks = make_float4(ak.x * inv, ak.y * inv, ak.z * inv, ak.w * inv);
    vs = make_float4(av.x * inv, av.y * inv, av.z * inv, av.w * inv);
  }
  long o = ((long)b * NKB + j) * E_ + c;
  *(float4*)(Kb + o) = ks;
  *(float4*)(Vb + o) = vs;
}

// ---------------------------------------------------------------------------
// Fused 3-level attention, one THREAD per query (no cross-lane ops).
// Scores are O(1) (|s|<~3) -> softmax without max-subtraction is exact-safe:
// level0 = single online pass (scalar l, one acc rescale); levels 1/2
// recompute (24 keys). K/V broadcast from LDS. Output -> bf16 hi/lo pair.
// ---------------------------------------------------------------------------
__device__ __forceinline__ float dotq(const float q[64], const float* kr) {
  float a0 = 0.f, a1 = 0.f, a2 = 0.f, a3 = 0.f;
#pragma unroll
  for (int i = 0; i < 64; i += 4) {
    float4 kv = *(const float4*)(kr + i);
    a0 += q[i] * kv.x; a1 += q[i + 1] * kv.y;
    a2 += q[i + 2] * kv.z; a3 += q[i + 3] * kv.w;
  }
  return (a0 + a1) + (a2 + a3);
}

__device__ __forceinline__ void pvacc(float acc[64], const float* vr, float p) {
#pragma unroll
  for (int i = 0; i < 64; i += 4) {
    float4 vv = *(const float4*)(vr + i);
    acc[i]     += p * vv.x; acc[i + 1] += p * vv.y;
    acc[i + 2] += p * vv.z; acc[i + 3] += p * vv.w;
  }
}

__global__ __launch_bounds__(256, 2) void attn_kernel(
    const float* __restrict__ Q, const float* __restrict__ Kb,
    const float* __restrict__ Vb, const float* __restrict__ lvl,
    short* __restrict__ AOh, short* __restrict__ AOl)
{
  __shared__ float Ks[NKB * DH_];
  __shared__ float Vs[NKB * DH_];
  const int tid = threadIdx.x;
  const int b = blockIdx.z, h = blockIdx.y;
  const long t0 = (long)blockIdx.x * 256;

  const float* Ksrc = Kb + (long)b * NKB * E_ + h * DH_;
  const float* Vsrc = Vb + (long)b * NKB * E_ + h * DH_;
  for (int g = tid; g < NKB * 16; g += 256) {
    int j = g >> 4, c = (g & 15) * 4;
    *(float4*)&Ks[j * 64 + c] = *(const float4*)(Ksrc + (long)j * E_ + c);
    *(float4*)&Vs[j * 64 + c] = *(const float4*)(Vsrc + (long)j * E_ + c);
  }

  float l0w = lvl[0], l1w = lvl[1], l2w = lvl[2];
  float lm = fmaxf(l0w, fmaxf(l1w, l2w));
  float e0 = __expf(l0w - lm), e1 = __expf(l1w - lm), e2 = __expf(l2w - lm);
  float einv = 1.0f / (e0 + e1 + e2);
  e0 *= einv; e1 *= einv; e2 *= einv;           // level weights w0,w1,w2

  float q[64];
  const float* Qrow = Q + ((long)b * T_ + t0 + tid) * E_ + h * DH_;
#pragma unroll
  for (int i = 0; i < 64; i += 4) {
    float4 v = *(const float4*)(Qrow + i);
    q[i] = v.x * 0.125f; q[i + 1] = v.y * 0.125f;     // fold 1/sqrt(64)
    q[i + 2] = v.z * 0.125f; q[i + 3] = v.w * 0.125f;
  }

  __syncthreads();

  float acc[64] = {};
  float lsum = 0.f;
  for (int j = 0; j < NK0; ++j) {              // level 0: single online pass
    float p = __expf(dotq(q, Ks + j * 64));
    lsum += p;
    pvacc(acc, Vs + j * 64, p);
  }
  float c0 = e0 / lsum;
#pragma unroll
  for (int i = 0; i < 64; ++i) acc[i] *= c0;

#pragma unroll
  for (int lv = 0; lv < 2; ++lv) {             // levels 1,2: recompute
    const int base = (lv == 0) ? 128 : 144;
    const int n    = (lv == 0) ? 16 : 8;
    const float wl = (lv == 0) ? e1 : e2;
    float ls = 0.f;
    for (int j = 0; j < n; ++j) ls += __expf(dotq(q, Ks + (base + j) * 64));
    float cw = wl / ls;
    for (int j = 0; j < n; ++j) {
      float p = __expf(dotq(q, Ks + (base + j) * 64)) * cw;
      pvacc(acc, Vs + (base + j) * 64, p);
    }
  }

  long orow = ((long)b * T_ + t0 + tid) * E_ + h * DH_;
#pragma unroll
  for (int i = 0; i < 64; i += 4) {
    short4 hs, ls4;
    bf16split(acc[i],     hs.x, ls4.x); bf16split(acc[i + 1], hs.y, ls4.y);
    bf16split(acc[i + 2], hs.z, ls4.z); bf16split(acc[i + 3], hs.w, ls4.w);
    *(short4*)(AOh + orow + i) = hs;
    *(short4*)(AOl + orow + i) = ls4;
  }
}

// ---------------------------------------------------------------------------
extern "C" void kernel_launch(void* const* d_in, const int* in_sizes, int n_in,
                              void* d_out, int out_size, void* d_ws, size_t ws_size,
                              hipStream_t stream)
{
  const float* x    = (const float*)d_in[0];
  const float* Wq_w = (const float*)d_in[1];
  const float* Wq_A = (const float*)d_in[2];
  const float* Wq_B = (const float*)d_in[3];
  const float* Wk_w = (const float*)d_in[4];
  const float* Wk_A = (const float*)d_in[5];
  const float* Wk_B = (const float*)d_in[6];
  const float* Wv_w = (const float*)d_in[7];
  const float* Wv_A = (const float*)d_in[8];
  const float* Wv_B = (const float*)d_in[9];
  const float* Wp   = (const float*)d_in[10];
  const float* lvl  = (const float*)d_in[11];
  float* out = (float*)d_out;

  // workspace layout — 302.0 MB total
  const long NXE = (long)B_ * T_ * E_;          // 33,554,432
  short* xh  = (short*)d_ws;
  short* xl  = xh + NXE;
  float* Qb  = (float*)(xl + NXE);
  short* Wqh = (short*)(Qb + NXE);
  short* Wql = Wqh + E_ * E_;
  short* Wkh = Wql + E_ * E_;
  short* Wkl = Wkh + E_ * E_;
  short* Wvh = Wkl + E_ * E_;
  short* Wvl = Wvh + E_ * E_;
  short* Wph = Wvl + E_ * E_;
  short* Wpl = Wph + E_ * E_;
  float* Kl  = (float*)(Wpl + E_ * E_);
  float* Vl  = Kl + (long)B_ * LAST * E_;
  // overlays (lifetime-disjoint):
  float* Kb  = (float*)Wqh;                     // over dead Wq/Wk/Wv splits (12MB>=10MB)
  float* Vb  = Kb + (long)B_ * NKB * E_;
  short* AOh = xh;                              // over dead x splits
  short* AOl = xl;

  // 1) splits
  split_kernel<<<4096, 256, 0, stream>>>(x, xh, xl, (int)(NXE / 4));
  weff_split_kernel<<<1024, 256, 0, stream>>>(Wq_w, Wq_A, Wq_B, Wqh, Wql);
  weff_split_kernel<<<1024, 256, 0, stream>>>(Wk_w, Wk_A, Wk_B, Wkh, Wkl);
  weff_split_kernel<<<1024, 256, 0, stream>>>(Wv_w, Wv_A, Wv_B, Wvh, Wvl);
  split_kernel<<<1024, 256, 0, stream>>>(Wp, Wph, Wpl, E_ * E_ / 4);

  // 2) Q projection (all 32768 rows)
  gemm_split_bt<false><<<dim3(8, 256, 1), 256, 0, stream>>>(
      xh, xl, Wqh, Wql, Qb, Wqh, Wql, Qb);

  // 3) K,V projections (gathered last-256 rows per batch), one launch
  gemm_split_bt<true><<<dim3(8, 16, 2), 256, 0, stream>>>(
      xh, xl, Wkh, Wkl, Kl, Wvh, Wvl, Vl);

  // 4) hierarchical bank
  bank_kernel<<<(B_ * NKB * 256) / 256, 256, 0, stream>>>(Kl, Vl, Kb, Vb);

  // 5) fused attention -> AO (bf16 hi/lo, overlaid on x splits)
  attn_kernel<<<dim3(T_ / 256, H_, B_), 256, 0, stream>>>(Qb, Kb, Vb, lvl, AOh, AOl);

  // 6) output projection -> d_out (fp32)
  gemm_split_bt<false><<<dim3(8, 256, 1), 256, 0, stream>>>(
      AOh, AOl, Wph, Wpl, out, Wph, Wpl, out);

  // 7) recon = 0.0
  hipMemsetAsync(out + NXE, 0, sizeof(float), stream);
}